// Round 9
// baseline (297.130 us; speedup 1.0000x reference)
//
#include <hip/hip_runtime.h>

#define Bn 1024
#define Tn 256

typedef __attribute__((ext_vector_type(4))) float f32x4;
typedef __attribute__((ext_vector_type(2))) float f32x2;
typedef __attribute__((ext_vector_type(8))) short short8;

static __device__ __forceinline__ unsigned pack_bf16_2(float lo, float hi) {
    unsigned ul = __float_as_uint(lo), uh = __float_as_uint(hi);
    ul = (ul + 0x7fffu + ((ul >> 16) & 1u)) >> 16;
    uh = (uh + 0x7fffu + ((uh >> 16) & 1u)) >> 16;
    return (ul & 0xffffu) | (uh << 16);
}

static __device__ __forceinline__ unsigned short f2bf(float f) {
    unsigned u = __float_as_uint(f);
    return (unsigned short)((u + 0x7fffu + ((u >> 16) & 1u)) >> 16);
}

__launch_bounds__(512, 2)
__global__ void bandit_rnn(const float* __restrict__ x,
                           const float* __restrict__ Wxr, const float* __restrict__ Wxz, const float* __restrict__ Wxn,
                           const float* __restrict__ Whr, const float* __restrict__ Whz, const float* __restrict__ Whn,
                           const float* __restrict__ bxr, const float* __restrict__ bxz, const float* __restrict__ bxn,
                           const float* __restrict__ brh, const float* __restrict__ bzh, const float* __restrict__ bnh,
                           const float* __restrict__ Wout, const float* __restrict__ bout,
                           float* __restrict__ out) {
    // comb tables as SoA b32: index n = 4*row + expert -> bank (16q+4j+e)%32,
    // uniform 2-way across the wave (free per m136). 13 components:
    // 0..2 Wxr, 3 bxr+brh, 4..6 Wxz, 7 bxz+bzh, 8..10 Wxn, 11 bxn, 12 bnh
    __shared__ float combP[13][520];
    // h16 chain stride 144 shorts -> (cc,q) address groups all exactly 2-way
    __shared__ __align__(16) unsigned short h16[2][4][144];
    __shared__ float xs[2][4][3];
    __shared__ unsigned modesArr[Tn];   // bits 0-7: 2-bit mode per chain; bits 8-11: pres mask
    // Wout MFMA fragments live in LDS (registers are at the 256/wave budget limit)
    __shared__ __align__(16) short8 aoutL[4][64];

    const int tid = threadIdx.x;
    const int w = tid >> 6;       // 8 waves
    const int lane = tid & 63;
    const int r16 = lane & 15, q = lane >> 4;
    const int cb = blockIdx.x * 4;
    const int grow = 16 * w + r16;   // this lane's A-row (M index)

    // ---------------- prologue ----------------
    for (int p = tid; p < 2 * 4 * 144; p += 512) ((unsigned short*)h16)[p] = 0;
    {
        int p = tid;              // p = 4*row + e  (512 threads cover all pairs)
        int row = p >> 2, e = p & 3;
        int src = e * 128 + row;
        const float* wr = Wxr + src * 3;
        const float* wz = Wxz + src * 3;
        const float* wn = Wxn + src * 3;
        combP[0][p] = wr[0];  combP[1][p] = wr[1];  combP[2][p] = wr[2];
        combP[3][p] = bxr[src] + brh[src];
        combP[4][p] = wz[0];  combP[5][p] = wz[1];  combP[6][p] = wz[2];
        combP[7][p] = bxz[src] + bzh[src];
        combP[8][p] = wn[0];  combP[9][p] = wn[1];  combP[10][p] = wn[2];
        combP[11][p] = bxn[src];
        combP[12][p] = bnh[src];
    }
    const float b0 = bout[0], b1 = bout[1];

    if (tid < Tn) {               // mode words + presence mask (selector depends only on x)
        const float* xp = x + (size_t)cb * (Tn * 3) + tid * 3;
        unsigned mword = 0, presm = 0;
#pragma unroll
        for (int c = 0; c < 4; ++c) {
            float x0 = xp[c * Tn * 3 + 0];
            float x1 = xp[c * Tn * 3 + 1];
            float x2 = xp[c * Tn * 3 + 2];
            unsigned mode = ((x1 > x0) ? 1u : 0u) + ((x2 > 0.5f) ? 2u : 0u);
            mword |= mode << (2 * c);
            presm |= 1u << mode;
        }
        modesArr[tid] = mword | (presm << 8);
    }
    if (tid < 12) {
        int c = tid / 3, j = tid % 3;
        xs[0][c][j] = x[(size_t)(cb + c) * (Tn * 3) + j];
    }
    if (tid < 64) {               // Wout fragments, lane-indexed (same for all waves)
#pragma unroll
        for (int kt = 0; kt < 4; ++kt) {
            union { short8 s; unsigned u[4]; } fr;
            fr.u[0] = fr.u[1] = fr.u[2] = fr.u[3] = 0;
            if (r16 < 2) {
                const float* wp = Wout + r16 * 128 + 32 * kt + 8 * q;
                fr.u[0] = pack_bf16_2(wp[0], wp[1]);
                fr.u[1] = pack_bf16_2(wp[2], wp[3]);
                fr.u[2] = pack_bf16_2(wp[4], wp[5]);
                fr.u[3] = pack_bf16_2(wp[6], wp[7]);
            }
            aoutL[kt][lane] = fr.s;
        }
    }

    // Wh weights: wave w owns rows [16w,16w+16); 48 short8 = 192 regs (AGPR side)
    short8 Afr[3][4][4];
    {
        const float* Wh[3] = {Whr, Whz, Whn};
#pragma unroll
        for (int g = 0; g < 3; ++g)
#pragma unroll
        for (int e = 0; e < 4; ++e)
#pragma unroll
        for (int kt = 0; kt < 4; ++kt) {
            const float* p = Wh[g] + (((e * 128) + grow) * 128 + 32 * kt + 8 * q);
            float4 a0 = *(const float4*)p;
            float4 a1 = *(const float4*)(p + 4);
            union { short8 s; unsigned u[4]; } fr;
            fr.u[0] = pack_bf16_2(a0.x, a0.y);
            fr.u[1] = pack_bf16_2(a0.z, a0.w);
            fr.u[2] = pack_bf16_2(a1.x, a1.y);
            fr.u[3] = pack_bf16_2(a1.z, a1.w);
            Afr[g][e][kt] = fr.s;
        }
    }

    // per-lane nonlin assignment: chain cc = r16&3, local row j* = r16>>2
    const int cc = r16 & 3;
    const bool jb0 = ((r16 >> 2) & 1) != 0;
    const bool jb1 = ((r16 >> 2) & 2) != 0;
    const int row = 16 * w + 4 * q + (r16 >> 2);
    float hpv = 0.f;              // f32 recurrent state (1 per lane)
    const f32x4 zacc = (f32x4){0.f, 0.f, 0.f, 0.f};
    __syncthreads();

    // ---------------- time loop: ONE barrier per step ----------------
#pragma unroll 1
    for (int t = 0; t < Tn; ++t) {
        const int tb = t & 1;
        // x_{t+1} prefetch on wave 7 (load issued before MFMAs, LDS write after)
        float xpre = 0.f; int xc = 0, xj = 0;
        const bool xload = (t + 1 < Tn) && (w == 7) && (lane < 12);
        if (xload) {
            xc = lane / 3; xj = lane % 3;
            xpre = x[(size_t)(cb + xc) * (Tn * 3) + (t + 1) * 3 + xj];
        }

        const unsigned m = modesArr[t];
        const unsigned pres = (m >> 8) & 15u;
        const int mode_c = (m >> (2 * cc)) & 3;

        short8 Bf[4];
#pragma unroll
        for (int kt = 0; kt < 4; ++kt)
            Bf[kt] = *(const short8*)&h16[tb][cc][32 * kt + 8 * q];

        // logits of step t-1 via MFMA on this step's Bf (= h after step t-1);
        // rotates across waves; Wout fragments come from LDS (register-budget fix)
        if (t > 0 && w == (t & 7)) {
            f32x4 alg = __builtin_amdgcn_mfma_f32_16x16x32_bf16(aoutL[0][lane], Bf[0], zacc, 0, 0, 0);
#pragma unroll
            for (int kt = 1; kt < 4; ++kt)
                alg = __builtin_amdgcn_mfma_f32_16x16x32_bf16(aoutL[kt][lane], Bf[kt], alg, 0, 0, 0);
            if (lane < 4)
                *(f32x2*)&out[((size_t)(cb + lane) * Tn + (t - 1)) * 2] =
                    (f32x2){alg[0] + b0, alg[1] + b1};
        }

        float selR = 0.f, selZ = 0.f, selN = 0.f;
#pragma unroll
        for (int e = 0; e < 4; ++e) {
            if (!(pres & (1u << e))) continue;   // block-uniform skip
            // first MFMA reads the shared zero quad as C (no per-expert acc init)
            f32x4 aR = __builtin_amdgcn_mfma_f32_16x16x32_bf16(Afr[0][e][0], Bf[0], zacc, 0, 0, 0);
            f32x4 aZ = __builtin_amdgcn_mfma_f32_16x16x32_bf16(Afr[1][e][0], Bf[0], zacc, 0, 0, 0);
            f32x4 aN = __builtin_amdgcn_mfma_f32_16x16x32_bf16(Afr[2][e][0], Bf[0], zacc, 0, 0, 0);
#pragma unroll
            for (int kt = 1; kt < 4; ++kt) {
                aR = __builtin_amdgcn_mfma_f32_16x16x32_bf16(Afr[0][e][kt], Bf[kt], aR, 0, 0, 0);
                aZ = __builtin_amdgcn_mfma_f32_16x16x32_bf16(Afr[1][e][kt], Bf[kt], aZ, 0, 0, 0);
                aN = __builtin_amdgcn_mfma_f32_16x16x32_bf16(Afr[2][e][kt], Bf[kt], aN, 0, 0, 0);
            }
            // per-lane scalar select of element j* = r16>>2, then mode-match select
            float vR = jb1 ? (jb0 ? aR[3] : aR[2]) : (jb0 ? aR[1] : aR[0]);
            float vZ = jb1 ? (jb0 ? aZ[3] : aZ[2]) : (jb0 ? aZ[1] : aZ[0]);
            float vN = jb1 ? (jb0 ? aN[3] : aN[2]) : (jb0 ? aN[1] : aN[0]);
            bool mym = (mode_c == e);
            selR = mym ? vR : selR;
            selZ = mym ? vZ : selZ;
            selN = mym ? vN : selN;
        }
        if (xload) xs[tb ^ 1][xc][xj] = xpre;

        // fused nonlinearity: lane owns (chain cc, row); comb reads are SoA b32,
        // uniform 2-way bank pattern (free)
        {
            const int n4 = (row << 2) + mode_c;
            float x0 = xs[tb][cc][0], x1 = xs[tb][cc][1], x2 = xs[tb][cc][2];
            float rp = selR + combP[3][n4]
                     + combP[0][n4] * x0 + combP[1][n4] * x1 + combP[2][n4] * x2;
            float zp = selZ + combP[7][n4]
                     + combP[4][n4] * x0 + combP[5][n4] * x1 + combP[6][n4] * x2;
            float xn = combP[11][n4]
                     + combP[8][n4] * x0 + combP[9][n4] * x1 + combP[10][n4] * x2;
            float bn = combP[12][n4];
            float r = __builtin_amdgcn_rcpf(1.f + __expf(-rp));
            float z = __builtin_amdgcn_rcpf(1.f + __expf(-zp));
            float npv = xn + r * (selN + bn);
            float ex = __expf(2.f * npv);
            float n = 1.f - 2.f * __builtin_amdgcn_rcpf(ex + 1.f);
            float h = n + z * (hpv - n);
            hpv = h;
            h16[tb ^ 1][cc][row] = f2bf(h);
        }
        __syncthreads();
    }

    // epilogue: logits of t = Tn-1 from h16[Tn&1] (holds final h)
    if (w == 0) {
        f32x4 alg = zacc;
#pragma unroll
        for (int kt = 0; kt < 4; ++kt) {
            short8 bfe = *(const short8*)&h16[Tn & 1][cc][32 * kt + 8 * q];
            alg = __builtin_amdgcn_mfma_f32_16x16x32_bf16(aoutL[kt][lane], bfe, alg, 0, 0, 0);
        }
        if (lane < 4)
            *(f32x2*)&out[((size_t)(cb + lane) * Tn + (Tn - 1)) * 2] =
                (f32x2){alg[0] + b0, alg[1] + b1};
    }
    // final hidden state hT from registers (one element per lane)
    out[(size_t)Bn * Tn * 2 + (size_t)(cb + cc) * 128 + row] = hpv;
}

extern "C" void kernel_launch(void* const* d_in, const int* in_sizes, int n_in,
                              void* d_out, int out_size, void* d_ws, size_t ws_size,
                              hipStream_t stream) {
    const float* xin = (const float*)d_in[0];
    const float* Wxr = (const float*)d_in[1];
    const float* Wxz = (const float*)d_in[2];
    const float* Wxn = (const float*)d_in[3];
    const float* Whr = (const float*)d_in[4];
    const float* Whz = (const float*)d_in[5];
    const float* Whn = (const float*)d_in[6];
    const float* bxr = (const float*)d_in[7];
    const float* bxz = (const float*)d_in[8];
    const float* bxn = (const float*)d_in[9];
    const float* brh = (const float*)d_in[10];
    const float* bzh = (const float*)d_in[11];
    const float* bnh = (const float*)d_in[12];
    const float* Wout = (const float*)d_in[13];
    const float* bout = (const float*)d_in[14];
    float* outp = (float*)d_out;

    hipLaunchKernelGGL(bandit_rnn, dim3(256), dim3(512), 0, stream,
                       xin, Wxr, Wxz, Wxn, Whr, Whz, Whn,
                       bxr, bxz, bxn, brh, bzh, bnh, Wout, bout, outp);
}

// Round 10
// 294.950 us; speedup vs baseline: 1.0074x; 1.0074x over previous
//
#include <hip/hip_runtime.h>

#define Bn 1024
#define Tn 256

typedef __attribute__((ext_vector_type(4))) float f32x4;
typedef __attribute__((ext_vector_type(2))) float f32x2;
typedef __attribute__((ext_vector_type(8))) short short8;

static __device__ __forceinline__ unsigned pack_bf16_2(float lo, float hi) {
    unsigned ul = __float_as_uint(lo), uh = __float_as_uint(hi);
    ul = (ul + 0x7fffu + ((ul >> 16) & 1u)) >> 16;
    uh = (uh + 0x7fffu + ((uh >> 16) & 1u)) >> 16;
    return (ul & 0xffffu) | (uh << 16);
}

static __device__ __forceinline__ unsigned short f2bf(float f) {
    unsigned u = __float_as_uint(f);
    return (unsigned short)((u + 0x7fffu + ((u >> 16) & 1u)) >> 16);
}

__launch_bounds__(512, 2)
__global__ void bandit_rnn(const float* __restrict__ x,
                           const float* __restrict__ Wxr, const float* __restrict__ Wxz, const float* __restrict__ Wxn,
                           const float* __restrict__ Whr, const float* __restrict__ Whz, const float* __restrict__ Whn,
                           const float* __restrict__ bxr, const float* __restrict__ bxz, const float* __restrict__ bxn,
                           const float* __restrict__ brh, const float* __restrict__ bzh, const float* __restrict__ bnh,
                           const float* __restrict__ Wout, const float* __restrict__ bout,
                           float* __restrict__ out) {
    // comb tables as SoA b32: index n = 4*row + expert -> uniform 2-way banks (free)
    __shared__ float combP[13][520];
    // h16 chain stride 144 shorts -> (cc,q) address groups all exactly 2-way
    __shared__ __align__(16) unsigned short h16[2][4][144];
    __shared__ float xs[2][4][3];
    __shared__ unsigned modesArr[Tn];   // bits 0-7: 2-bit mode per chain; bits 8-11: pres mask
    // Wout MFMA fragments live in LDS (registers are at the 256/wave budget limit)
    __shared__ __align__(16) short8 aoutL[4][64];

    const int tid = threadIdx.x;
    const int w = tid >> 6;       // 8 waves
    const int lane = tid & 63;
    const int r16 = lane & 15, q = lane >> 4;
    const int cb = blockIdx.x * 4;
    const int grow = 16 * w + r16;   // this lane's A-row (M index)

    // ---------------- prologue ----------------
    for (int p = tid; p < 2 * 4 * 144; p += 512) ((unsigned short*)h16)[p] = 0;
    {
        int p = tid;              // p = 4*row + e  (512 threads cover all pairs)
        int row = p >> 2, e = p & 3;
        int src = e * 128 + row;
        const float* wr = Wxr + src * 3;
        const float* wz = Wxz + src * 3;
        const float* wn = Wxn + src * 3;
        combP[0][p] = wr[0];  combP[1][p] = wr[1];  combP[2][p] = wr[2];
        combP[3][p] = bxr[src] + brh[src];
        combP[4][p] = wz[0];  combP[5][p] = wz[1];  combP[6][p] = wz[2];
        combP[7][p] = bxz[src] + bzh[src];
        combP[8][p] = wn[0];  combP[9][p] = wn[1];  combP[10][p] = wn[2];
        combP[11][p] = bxn[src];
        combP[12][p] = bnh[src];
    }
    const float b0 = bout[0], b1 = bout[1];

    if (tid < Tn) {               // mode words + presence mask (selector depends only on x)
        const float* xp = x + (size_t)cb * (Tn * 3) + tid * 3;
        unsigned mword = 0, presm = 0;
#pragma unroll
        for (int c = 0; c < 4; ++c) {
            float x0 = xp[c * Tn * 3 + 0];
            float x1 = xp[c * Tn * 3 + 1];
            float x2 = xp[c * Tn * 3 + 2];
            unsigned mode = ((x1 > x0) ? 1u : 0u) + ((x2 > 0.5f) ? 2u : 0u);
            mword |= mode << (2 * c);
            presm |= 1u << mode;
        }
        modesArr[tid] = mword | (presm << 8);
    }
    if (tid < 12) {
        int c = tid / 3, j = tid % 3;
        xs[0][c][j] = x[(size_t)(cb + c) * (Tn * 3) + j];
    }
    if (tid < 64) {               // Wout fragments, lane-indexed (same for all waves)
#pragma unroll
        for (int kt = 0; kt < 4; ++kt) {
            union { short8 s; unsigned u[4]; } fr;
            fr.u[0] = fr.u[1] = fr.u[2] = fr.u[3] = 0;
            if (r16 < 2) {
                const float* wp = Wout + r16 * 128 + 32 * kt + 8 * q;
                fr.u[0] = pack_bf16_2(wp[0], wp[1]);
                fr.u[1] = pack_bf16_2(wp[2], wp[3]);
                fr.u[2] = pack_bf16_2(wp[4], wp[5]);
                fr.u[3] = pack_bf16_2(wp[6], wp[7]);
            }
            aoutL[kt][lane] = fr.s;
        }
    }

    // Wh weights: wave w owns rows [16w,16w+16); 48 short8 = 192 regs (AGPR side)
    short8 Afr[3][4][4];
    {
        const float* Wh[3] = {Whr, Whz, Whn};
#pragma unroll
        for (int g = 0; g < 3; ++g)
#pragma unroll
        for (int e = 0; e < 4; ++e)
#pragma unroll
        for (int kt = 0; kt < 4; ++kt) {
            const float* p = Wh[g] + (((e * 128) + grow) * 128 + 32 * kt + 8 * q);
            float4 a0 = *(const float4*)p;
            float4 a1 = *(const float4*)(p + 4);
            union { short8 s; unsigned u[4]; } fr;
            fr.u[0] = pack_bf16_2(a0.x, a0.y);
            fr.u[1] = pack_bf16_2(a0.z, a0.w);
            fr.u[2] = pack_bf16_2(a1.x, a1.y);
            fr.u[3] = pack_bf16_2(a1.z, a1.w);
            Afr[g][e][kt] = fr.s;
        }
    }

    // per-lane nonlin assignment: chain cc = r16&3, local row j* = r16>>2
    const int cc = r16 & 3;
    const bool jb0 = ((r16 >> 2) & 1) != 0;
    const bool jb1 = ((r16 >> 2) & 2) != 0;
    const int row = 16 * w + 4 * q + (r16 >> 2);
    float hpv = 0.f;              // f32 recurrent state (1 per lane)
    const f32x4 zacc = (f32x4){0.f, 0.f, 0.f, 0.f};
    const float L2E = 1.44269504f;     // log2(e)
    const float L2E2 = 2.88539008f;    // 2*log2(e)
    __syncthreads();

    // mode word carried in a register across the barrier (kills the step-start
    // LDS-read dependency on the pres branch)
    unsigned m_cur = modesArr[0];

    // ---------------- time loop: ONE barrier per step ----------------
#pragma unroll 1
    for (int t = 0; t < Tn; ++t) {
        const int tb = t & 1;
        // x_{t+1} prefetch on wave 7 (load issued before MFMAs, LDS write after)
        float xpre = 0.f; int xc = 0, xj = 0;
        const bool xload = (t + 1 < Tn) && (w == 7) && (lane < 12);
        if (xload) {
            xc = lane / 3; xj = lane % 3;
            xpre = x[(size_t)(cb + xc) * (Tn * 3) + (t + 1) * 3 + xj];
        }

        const unsigned m = m_cur;
        if (t + 1 < Tn) m_cur = modesArr[t + 1];   // prefetch for next step
        const unsigned pres = (m >> 8) & 15u;
        const int mode_c = (m >> (2 * cc)) & 3;

        short8 Bf[4];
#pragma unroll
        for (int kt = 0; kt < 4; ++kt)
            Bf[kt] = *(const short8*)&h16[tb][cc][32 * kt + 8 * q];

        float selR = 0.f, selZ = 0.f, selN = 0.f;
#pragma unroll
        for (int e = 0; e < 4; ++e) {
            if (!(pres & (1u << e))) continue;   // block-uniform skip
            // first MFMA reads the shared zero quad as C (no per-expert acc init)
            f32x4 aR = __builtin_amdgcn_mfma_f32_16x16x32_bf16(Afr[0][e][0], Bf[0], zacc, 0, 0, 0);
            f32x4 aZ = __builtin_amdgcn_mfma_f32_16x16x32_bf16(Afr[1][e][0], Bf[0], zacc, 0, 0, 0);
            f32x4 aN = __builtin_amdgcn_mfma_f32_16x16x32_bf16(Afr[2][e][0], Bf[0], zacc, 0, 0, 0);
#pragma unroll
            for (int kt = 1; kt < 4; ++kt) {
                aR = __builtin_amdgcn_mfma_f32_16x16x32_bf16(Afr[0][e][kt], Bf[kt], aR, 0, 0, 0);
                aZ = __builtin_amdgcn_mfma_f32_16x16x32_bf16(Afr[1][e][kt], Bf[kt], aZ, 0, 0, 0);
                aN = __builtin_amdgcn_mfma_f32_16x16x32_bf16(Afr[2][e][kt], Bf[kt], aN, 0, 0, 0);
            }
            // per-lane scalar select of element j* = r16>>2, then mode-match select
            float vR = jb1 ? (jb0 ? aR[3] : aR[2]) : (jb0 ? aR[1] : aR[0]);
            float vZ = jb1 ? (jb0 ? aZ[3] : aZ[2]) : (jb0 ? aZ[1] : aZ[0]);
            float vN = jb1 ? (jb0 ? aN[3] : aN[2]) : (jb0 ? aN[1] : aN[0]);
            bool mym = (mode_c == e);
            selR = mym ? vR : selR;
            selZ = mym ? vZ : selZ;
            selN = mym ? vN : selN;
        }
        if (xload) xs[tb ^ 1][xc][xj] = xpre;

        // logits of step t-1, issued AFTER the gate MFMAs: the matrix pipe is idle
        // during the nonlinearity, so these overlap instead of delaying the shared
        // MFMA phase (barrier-skew removal). Bf still holds h_{t-1}; h16[tb] is
        // not rewritten this step.
        if (t > 0 && w == (t & 7)) {
            f32x4 alg = __builtin_amdgcn_mfma_f32_16x16x32_bf16(aoutL[0][lane], Bf[0], zacc, 0, 0, 0);
#pragma unroll
            for (int kt = 1; kt < 4; ++kt)
                alg = __builtin_amdgcn_mfma_f32_16x16x32_bf16(aoutL[kt][lane], Bf[kt], alg, 0, 0, 0);
            if (lane < 4)
                *(f32x2*)&out[((size_t)(cb + lane) * Tn + (t - 1)) * 2] =
                    (f32x2){alg[0] + b0, alg[1] + b1};
        }

        // fused nonlinearity: lane owns (chain cc, row); comb reads are SoA b32
        {
            const int n4 = (row << 2) + mode_c;
            float x0 = xs[tb][cc][0], x1 = xs[tb][cc][1], x2 = xs[tb][cc][2];
            float rp = selR + combP[3][n4]
                     + combP[0][n4] * x0 + combP[1][n4] * x1 + combP[2][n4] * x2;
            float zp = selZ + combP[7][n4]
                     + combP[4][n4] * x0 + combP[5][n4] * x1 + combP[6][n4] * x2;
            float xn = combP[11][n4]
                     + combP[8][n4] * x0 + combP[9][n4] * x1 + combP[10][n4] * x2;
            float bn = combP[12][n4];
            float r = __builtin_amdgcn_rcpf(1.f + __builtin_amdgcn_exp2f(-rp * L2E));
            float z = __builtin_amdgcn_rcpf(1.f + __builtin_amdgcn_exp2f(-zp * L2E));
            float npv = xn + r * (selN + bn);
            float ex = __builtin_amdgcn_exp2f(npv * L2E2);
            float n = 1.f - 2.f * __builtin_amdgcn_rcpf(ex + 1.f);
            float h = n + z * (hpv - n);
            hpv = h;
            h16[tb ^ 1][cc][row] = f2bf(h);
        }
        __syncthreads();
    }

    // epilogue: logits of t = Tn-1 from h16[Tn&1] (holds final h)
    if (w == 0) {
        f32x4 alg = zacc;
#pragma unroll
        for (int kt = 0; kt < 4; ++kt) {
            short8 bfe = *(const short8*)&h16[Tn & 1][cc][32 * kt + 8 * q];
            alg = __builtin_amdgcn_mfma_f32_16x16x32_bf16(aoutL[kt][lane], bfe, alg, 0, 0, 0);
        }
        if (lane < 4)
            *(f32x2*)&out[((size_t)(cb + lane) * Tn + (Tn - 1)) * 2] =
                (f32x2){alg[0] + b0, alg[1] + b1};
    }
    // final hidden state hT from registers (one element per lane)
    out[(size_t)Bn * Tn * 2 + (size_t)(cb + cc) * 128 + row] = hpv;
}

extern "C" void kernel_launch(void* const* d_in, const int* in_sizes, int n_in,
                              void* d_out, int out_size, void* d_ws, size_t ws_size,
                              hipStream_t stream) {
    const float* xin = (const float*)d_in[0];
    const float* Wxr = (const float*)d_in[1];
    const float* Wxz = (const float*)d_in[2];
    const float* Wxn = (const float*)d_in[3];
    const float* Whr = (const float*)d_in[4];
    const float* Whz = (const float*)d_in[5];
    const float* Whn = (const float*)d_in[6];
    const float* bxr = (const float*)d_in[7];
    const float* bxz = (const float*)d_in[8];
    const float* bxn = (const float*)d_in[9];
    const float* brh = (const float*)d_in[10];
    const float* bzh = (const float*)d_in[11];
    const float* bnh = (const float*)d_in[12];
    const float* Wout = (const float*)d_in[13];
    const float* bout = (const float*)d_in[14];
    float* outp = (float*)d_out;

    hipLaunchKernelGGL(bandit_rnn, dim3(256), dim3(512), 0, stream,
                       xin, Wxr, Wxz, Wxn, Whr, Whz, Whn,
                       bxr, bxz, bxn, brh, bzh, bnh, Wout, bout, outp);
}

// Round 11
// 290.901 us; speedup vs baseline: 1.0214x; 1.0139x over previous
//
#include <hip/hip_runtime.h>

#define Bn 1024
#define Tn 256

typedef __attribute__((ext_vector_type(4))) float f32x4;
typedef __attribute__((ext_vector_type(2))) float f32x2;
typedef __attribute__((ext_vector_type(8))) short short8;

static __device__ __forceinline__ unsigned pack_bf16_2(float lo, float hi) {
    unsigned ul = __float_as_uint(lo), uh = __float_as_uint(hi);
    ul = (ul + 0x7fffu + ((ul >> 16) & 1u)) >> 16;
    uh = (uh + 0x7fffu + ((uh >> 16) & 1u)) >> 16;
    return (ul & 0xffffu) | (uh << 16);
}

static __device__ __forceinline__ unsigned short f2bf(float f) {
    unsigned u = __float_as_uint(f);
    return (unsigned short)((u + 0x7fffu + ((u >> 16) & 1u)) >> 16);
}

#define L2E  1.44269504f     // log2(e): folded into r/z gate weights
#define L2E2 2.88539008f     // 2*log2(e): folded into n gate weights

__launch_bounds__(512, 2)
__global__ void bandit_rnn(const float* __restrict__ x,
                           const float* __restrict__ Wxr, const float* __restrict__ Wxz, const float* __restrict__ Wxn,
                           const float* __restrict__ Whr, const float* __restrict__ Whz, const float* __restrict__ Whn,
                           const float* __restrict__ bxr, const float* __restrict__ bxz, const float* __restrict__ bxn,
                           const float* __restrict__ brh, const float* __restrict__ bzh, const float* __restrict__ bnh,
                           const float* __restrict__ Wout, const float* __restrict__ bout,
                           float* __restrict__ out) {
    // comb tables as SoA b32: index n = 4*row + expert -> uniform 2-way banks (free)
    __shared__ float combP[13][520];
    // h16 chain stride 144 shorts -> (cc,q) address groups all exactly 2-way
    __shared__ __align__(16) unsigned short h16[2][4][144];
    __shared__ float xs[2][4][3];
    __shared__ unsigned modesArr[Tn];   // bits 0-7: 2-bit mode per chain; bits 8-11: pres mask
    // Wout MFMA fragments live in LDS (registers are at the 256/wave budget limit)
    __shared__ __align__(16) short8 aoutL[4][64];

    const int tid = threadIdx.x;
    const int w = tid >> 6;       // 8 waves
    const int lane = tid & 63;
    const int r16 = lane & 15, q = lane >> 4;
    const int cb = blockIdx.x * 4;
    const int grow = 16 * w + r16;   // this lane's A-row (M index)

    // ---------------- prologue ----------------
    for (int p = tid; p < 2 * 4 * 144; p += 512) ((unsigned short*)h16)[p] = 0;
    {
        int p = tid;              // p = 4*row + e  (512 threads cover all pairs)
        int row = p >> 2, e = p & 3;
        int src = e * 128 + row;
        const float* wr = Wxr + src * 3;
        const float* wz = Wxz + src * 3;
        const float* wn = Wxn + src * 3;
        // r/z entries pre-scaled by log2e, n entries by 2*log2e (exp2-form gates)
        combP[0][p] = wr[0] * L2E;  combP[1][p] = wr[1] * L2E;  combP[2][p] = wr[2] * L2E;
        combP[3][p] = (bxr[src] + brh[src]) * L2E;
        combP[4][p] = wz[0] * L2E;  combP[5][p] = wz[1] * L2E;  combP[6][p] = wz[2] * L2E;
        combP[7][p] = (bxz[src] + bzh[src]) * L2E;
        combP[8][p] = wn[0] * L2E2; combP[9][p] = wn[1] * L2E2; combP[10][p] = wn[2] * L2E2;
        combP[11][p] = bxn[src] * L2E2;
        combP[12][p] = bnh[src] * L2E2;
    }
    const float b0 = bout[0], b1 = bout[1];

    if (tid < Tn) {               // mode words + presence mask (selector depends only on x)
        const float* xp = x + (size_t)cb * (Tn * 3) + tid * 3;
        unsigned mword = 0, presm = 0;
#pragma unroll
        for (int c = 0; c < 4; ++c) {
            float x0 = xp[c * Tn * 3 + 0];
            float x1 = xp[c * Tn * 3 + 1];
            float x2 = xp[c * Tn * 3 + 2];
            unsigned mode = ((x1 > x0) ? 1u : 0u) + ((x2 > 0.5f) ? 2u : 0u);
            mword |= mode << (2 * c);
            presm |= 1u << mode;
        }
        modesArr[tid] = mword | (presm << 8);
    }
    if (tid < 12) {
        int c = tid / 3, j = tid % 3;
        xs[0][c][j] = x[(size_t)(cb + c) * (Tn * 3) + j];
    }
    if (tid < 64) {               // Wout fragments, lane-indexed (same for all waves)
#pragma unroll
        for (int kt = 0; kt < 4; ++kt) {
            union { short8 s; unsigned u[4]; } fr;
            fr.u[0] = fr.u[1] = fr.u[2] = fr.u[3] = 0;
            if (r16 < 2) {
                const float* wp = Wout + r16 * 128 + 32 * kt + 8 * q;
                fr.u[0] = pack_bf16_2(wp[0], wp[1]);
                fr.u[1] = pack_bf16_2(wp[2], wp[3]);
                fr.u[2] = pack_bf16_2(wp[4], wp[5]);
                fr.u[3] = pack_bf16_2(wp[6], wp[7]);
            }
            aoutL[kt][lane] = fr.s;
        }
    }

    // Wh weights: wave w owns rows [16w,16w+16); 48 short8 = 192 regs (AGPR side).
    // r/z gates pre-scaled by log2e, n gate by 2*log2e (matches comb scaling).
    short8 Afr[3][4][4];
    {
        const float* Wh[3] = {Whr, Whz, Whn};
        const float gs[3] = {L2E, L2E, L2E2};
#pragma unroll
        for (int g = 0; g < 3; ++g)
#pragma unroll
        for (int e = 0; e < 4; ++e)
#pragma unroll
        for (int kt = 0; kt < 4; ++kt) {
            const float* p = Wh[g] + (((e * 128) + grow) * 128 + 32 * kt + 8 * q);
            float4 a0 = *(const float4*)p;
            float4 a1 = *(const float4*)(p + 4);
            float s = gs[g];
            union { short8 s; unsigned u[4]; } fr;
            fr.u[0] = pack_bf16_2(a0.x * s, a0.y * s);
            fr.u[1] = pack_bf16_2(a0.z * s, a0.w * s);
            fr.u[2] = pack_bf16_2(a1.x * s, a1.y * s);
            fr.u[3] = pack_bf16_2(a1.z * s, a1.w * s);
            Afr[g][e][kt] = fr.s;
        }
    }

    // per-lane nonlin assignment: chain cc = r16&3, local row j* = r16>>2
    const int cc = r16 & 3;
    const bool jb0 = ((r16 >> 2) & 1) != 0;
    const bool jb1 = ((r16 >> 2) & 2) != 0;
    const int row = 16 * w + 4 * q + (r16 >> 2);
    float hpv = 0.f;              // f32 recurrent state (1 per lane)
    const f32x4 zacc = (f32x4){0.f, 0.f, 0.f, 0.f};
    __syncthreads();

    // mode word carried in a register across the barrier
    unsigned m_cur = modesArr[0];

    // ---------------- time loop: ONE lgkmcnt-only barrier per step ----------------
    // __syncthreads() would drain vmcnt(0) before s_barrier, putting the logit
    // wave's global store (~200-500 cy to L2) on every step's critical path.
    // LDS ordering (h16/xs) only needs lgkmcnt(0); global stores may float.
#pragma unroll 1
    for (int t = 0; t < Tn; ++t) {
        const int tb = t & 1;
        // x_{t+1} prefetch on wave 7 (load issued before MFMAs, LDS write after)
        float xpre = 0.f; int xc = 0, xj = 0;
        const bool xload = (t + 1 < Tn) && (w == 7) && (lane < 12);
        if (xload) {
            xc = lane / 3; xj = lane % 3;
            xpre = x[(size_t)(cb + xc) * (Tn * 3) + (t + 1) * 3 + xj];
        }

        const unsigned m = m_cur;
        if (t + 1 < Tn) m_cur = modesArr[t + 1];   // prefetch for next step
        const unsigned pres = (m >> 8) & 15u;
        const int mode_c = (m >> (2 * cc)) & 3;

        short8 Bf[4];
#pragma unroll
        for (int kt = 0; kt < 4; ++kt)
            Bf[kt] = *(const short8*)&h16[tb][cc][32 * kt + 8 * q];

        float selR = 0.f, selZ = 0.f, selN = 0.f;
#pragma unroll
        for (int e = 0; e < 4; ++e) {
            if (!(pres & (1u << e))) continue;   // block-uniform skip
            // first MFMA reads the shared zero quad as C (no per-expert acc init)
            f32x4 aR = __builtin_amdgcn_mfma_f32_16x16x32_bf16(Afr[0][e][0], Bf[0], zacc, 0, 0, 0);
            f32x4 aZ = __builtin_amdgcn_mfma_f32_16x16x32_bf16(Afr[1][e][0], Bf[0], zacc, 0, 0, 0);
            f32x4 aN = __builtin_amdgcn_mfma_f32_16x16x32_bf16(Afr[2][e][0], Bf[0], zacc, 0, 0, 0);
#pragma unroll
            for (int kt = 1; kt < 4; ++kt) {
                aR = __builtin_amdgcn_mfma_f32_16x16x32_bf16(Afr[0][e][kt], Bf[kt], aR, 0, 0, 0);
                aZ = __builtin_amdgcn_mfma_f32_16x16x32_bf16(Afr[1][e][kt], Bf[kt], aZ, 0, 0, 0);
                aN = __builtin_amdgcn_mfma_f32_16x16x32_bf16(Afr[2][e][kt], Bf[kt], aN, 0, 0, 0);
            }
            // per-lane scalar select of element j* = r16>>2, then mode-match select
            float vR = jb1 ? (jb0 ? aR[3] : aR[2]) : (jb0 ? aR[1] : aR[0]);
            float vZ = jb1 ? (jb0 ? aZ[3] : aZ[2]) : (jb0 ? aZ[1] : aZ[0]);
            float vN = jb1 ? (jb0 ? aN[3] : aN[2]) : (jb0 ? aN[1] : aN[0]);
            bool mym = (mode_c == e);
            selR = mym ? vR : selR;
            selZ = mym ? vZ : selZ;
            selN = mym ? vN : selN;
        }
        if (xload) xs[tb ^ 1][xc][xj] = xpre;

        // logits of step t-1, issued AFTER the gate MFMAs (matrix pipe idle during
        // nonlin); store is NOT drained before the barrier anymore.
        if (t > 0 && w == (t & 7)) {
            f32x4 alg = __builtin_amdgcn_mfma_f32_16x16x32_bf16(aoutL[0][lane], Bf[0], zacc, 0, 0, 0);
#pragma unroll
            for (int kt = 1; kt < 4; ++kt)
                alg = __builtin_amdgcn_mfma_f32_16x16x32_bf16(aoutL[kt][lane], Bf[kt], alg, 0, 0, 0);
            if (lane < 4)
                *(f32x2*)&out[((size_t)(cb + lane) * Tn + (t - 1)) * 2] =
                    (f32x2){alg[0] + b0, alg[1] + b1};
        }

        // fused nonlinearity (exp2-form, scales pre-folded into weights)
        {
            const int n4 = (row << 2) + mode_c;
            float x0 = xs[tb][cc][0], x1 = xs[tb][cc][1], x2 = xs[tb][cc][2];
            float rp = selR + combP[3][n4]
                     + combP[0][n4] * x0 + combP[1][n4] * x1 + combP[2][n4] * x2;
            float zp = selZ + combP[7][n4]
                     + combP[4][n4] * x0 + combP[5][n4] * x1 + combP[6][n4] * x2;
            float xn = combP[11][n4]
                     + combP[8][n4] * x0 + combP[9][n4] * x1 + combP[10][n4] * x2;
            float bn = combP[12][n4];
            float r = __builtin_amdgcn_rcpf(1.f + __builtin_amdgcn_exp2f(-rp));
            float z = __builtin_amdgcn_rcpf(1.f + __builtin_amdgcn_exp2f(-zp));
            float npv = xn + r * (selN + bn);
            float ex = __builtin_amdgcn_exp2f(npv);
            float n = 1.f - 2.f * __builtin_amdgcn_rcpf(ex + 1.f);
            float h = n + z * (hpv - n);
            hpv = h;
            h16[tb ^ 1][cc][row] = f2bf(h);
        }
        // lgkmcnt-only barrier: drain LDS writes, let global ops float across
        asm volatile("s_waitcnt lgkmcnt(0)" ::: "memory");
        __builtin_amdgcn_s_barrier();
    }

    // epilogue: logits of t = Tn-1 from h16[Tn&1] (holds final h)
    if (w == 0) {
        f32x4 alg = zacc;
#pragma unroll
        for (int kt = 0; kt < 4; ++kt) {
            short8 bfe = *(const short8*)&h16[Tn & 1][cc][32 * kt + 8 * q];
            alg = __builtin_amdgcn_mfma_f32_16x16x32_bf16(aoutL[kt][lane], bfe, alg, 0, 0, 0);
        }
        if (lane < 4)
            *(f32x2*)&out[((size_t)(cb + lane) * Tn + (Tn - 1)) * 2] =
                (f32x2){alg[0] + b0, alg[1] + b1};
    }
    // final hidden state hT from registers (one element per lane)
    out[(size_t)Bn * Tn * 2 + (size_t)(cb + cc) * 128 + row] = hpv;
}

extern "C" void kernel_launch(void* const* d_in, const int* in_sizes, int n_in,
                              void* d_out, int out_size, void* d_ws, size_t ws_size,
                              hipStream_t stream) {
    const float* xin = (const float*)d_in[0];
    const float* Wxr = (const float*)d_in[1];
    const float* Wxz = (const float*)d_in[2];
    const float* Wxn = (const float*)d_in[3];
    const float* Whr = (const float*)d_in[4];
    const float* Whz = (const float*)d_in[5];
    const float* Whn = (const float*)d_in[6];
    const float* bxr = (const float*)d_in[7];
    const float* bxz = (const float*)d_in[8];
    const float* bxn = (const float*)d_in[9];
    const float* brh = (const float*)d_in[10];
    const float* bzh = (const float*)d_in[11];
    const float* bnh = (const float*)d_in[12];
    const float* Wout = (const float*)d_in[13];
    const float* bout = (const float*)d_in[14];
    float* outp = (float*)d_out;

    hipLaunchKernelGGL(bandit_rnn, dim3(256), dim3(512), 0, stream,
                       xin, Wxr, Wxz, Wxn, Whr, Whz, Whn,
                       bxr, bxz, bxn, brh, bzh, bnh, Wout, bout, outp);
}